// Round 17
// baseline (655.731 us; speedup 1.0000x reference)
//
#include <hip/hip_runtime.h>
#include <hip/hip_bf16.h>

#define NN 50000
#define EE 800000
#define DD 100
#define HH 16
#define CC 40
#define NCELL 12
#define NB_SCAN 49   // ceil(50000/1024)

typedef __hip_bfloat162 bf2;
typedef short bf16x8 __attribute__((ext_vector_type(8)));
typedef float f32x4 __attribute__((ext_vector_type(4)));

__device__ __forceinline__ float2 b2f2(bf2 v) { return __bfloat1622float2(v); }
__device__ __forceinline__ bf2 f22b2(float f0, float f1) {
    float2 t; t.x = f0; t.y = f1;
    return __float22bfloat162_rn(t);
}
__device__ __forceinline__ unsigned short f2b(float f) {
    __hip_bfloat16 h = __float2bfloat16(f);
    return *reinterpret_cast<unsigned short*>(&h);
}

// ---------------- graph preprocessing ----------------

__global__ __launch_bounds__(256) void k_hist(const int* __restrict__ er, int* __restrict__ cnt) {
    int e = blockIdx.x * 256 + threadIdx.x;
    if (e < EE) atomicAdd(&cnt[er[e]], 1);
}

__global__ __launch_bounds__(1024) void k_scan1(const int* __restrict__ cnt, int* __restrict__ rp,
                                                int* __restrict__ bsum) {
    __shared__ int lds[1024];
    int t = threadIdx.x, i = blockIdx.x * 1024 + t;
    int v = (i < NN) ? cnt[i] : 0;
    lds[t] = v;
    __syncthreads();
    #pragma unroll
    for (int off = 1; off < 1024; off <<= 1) {
        int x = lds[t];
        int y = (t >= off) ? lds[t - off] : 0;
        __syncthreads();
        lds[t] = x + y;
        __syncthreads();
    }
    if (i < NN) rp[i] = lds[t] - v;
    if (t == 1023) bsum[blockIdx.x] = lds[1023];
}

__global__ __launch_bounds__(64) void k_scan2(int* __restrict__ bsum) {
    int t = threadIdx.x;
    int orig = (t < NB_SCAN) ? bsum[t] : 0;
    int v = orig;
    #pragma unroll
    for (int off = 1; off < 64; off <<= 1) {
        int y = __shfl_up(v, off);
        if (t >= off) v += y;
    }
    if (t < NB_SCAN) bsum[t] = v - orig;
    if (t == NB_SCAN - 1) bsum[NB_SCAN] = v;
}

// scan finalize + dinv + degree-bucket histogram (folded)
__global__ __launch_bounds__(256) void k_scan3(int* __restrict__ rp, int* __restrict__ cursor,
                                               const int* __restrict__ bsum, const int* __restrict__ cnt,
                                               float* __restrict__ dinv, int* __restrict__ dbkt) {
    int i = blockIdx.x * 256 + threadIdx.x;
    if (i < NN) {
        int v = rp[i] + bsum[i >> 10];
        rp[i] = v;
        cursor[i] = v;
        int c = cnt[i];
        dinv[i] = rsqrtf((float)(c + 1));   // +1 self loop
        atomicAdd(&dbkt[c < 63 ? c : 63], 1);
    }
    if (i == 0) rp[NN] = bsum[NB_SCAN];
}

// 64-bucket exclusive scan (degree buckets)
__global__ __launch_bounds__(64) void k_dscan(int* __restrict__ dbkt) {
    int t = threadIdx.x;
    int orig = dbkt[t];
    int v = orig;
    #pragma unroll
    for (int off = 1; off < 64; off <<= 1) {
        int y = __shfl_up(v, off);
        if (t >= off) v += y;
    }
    dbkt[t] = v - orig;   // exclusive; becomes the scatter cursor
}

// scatter rows into degree-sorted permutation
__global__ __launch_bounds__(256) void k_dfill(const int* __restrict__ cnt, int* __restrict__ dbkt,
                                               int* __restrict__ perm) {
    int i = blockIdx.x * 256 + threadIdx.x;
    if (i >= NN) return;
    int c = cnt[i];
    int p = atomicAdd(&dbkt[c < 63 ? c : 63], 1);
    perm[p] = i;
}

// CSR fill: single 8B scatter per edge {col, bits(val)}
__global__ __launch_bounds__(256) void k_fill(const int* __restrict__ er, const int* __restrict__ ec,
                                              const float* __restrict__ dinv, int* __restrict__ cursor,
                                              int2* __restrict__ ecv) {
    int e = blockIdx.x * 256 + threadIdx.x;
    if (e >= EE) return;
    int r = er[e], c = ec[e];
    int p = atomicAdd(&cursor[r], 1);
    float v = dinv[r] * dinv[c];
    ecv[p] = make_int2(c, __float_as_int(v));
}

// ---------------- merged weight prep: W1T | WoutT | Wpack | shift192 ----------------
#define PW_W1T   (192 * 128)
#define PW_WT    (48 * 480)
#define PW_W2P   (30 * 16 * 32)
#define PW_TOTAL (PW_W1T + PW_WT + PW_W2P + 192)
__global__ __launch_bounds__(256) void k_prep(const float* __restrict__ W1, const float* __restrict__ Wout,
                                              const float* __restrict__ W2, const float* __restrict__ b1,
                                              const float* __restrict__ gamma, const float* __restrict__ beta,
                                              const float* __restrict__ bn_mean, const float* __restrict__ bn_var,
                                              unsigned short* __restrict__ W1T, unsigned short* __restrict__ WoutT,
                                              unsigned short* __restrict__ Wpack, float* __restrict__ shift192) {
    int idx = blockIdx.x * 256 + threadIdx.x;
    if (idx < PW_W1T) {
        int c = idx / 128, k = idx % 128;
        int g = c / 48, i = c % 48;
        int cell = (i / 16) * 4 + g, j = i % 16;
        float sc = gamma[cell * HH + j] * rsqrtf(bn_var[cell * HH + j] + 1e-5f);
        float v = (k < DD) ? W1[((size_t)cell * DD + k) * HH + j] * sc : 0.f;
        W1T[idx] = f2b(v);
        return;
    }
    idx -= PW_W1T;
    if (idx < PW_WT) {
        int c = idx / 480, k = idx % 480;
        float v = (c < CC) ? Wout[(size_t)k * CC + c] : 0.f;
        WoutT[idx] = f2b(v);
        return;
    }
    idx -= PW_WT;
    if (idx < PW_W2P) {
        int t = idx / 512, bcol = (idx / 32) % 16, k = idx % 32;
        int c = 16 * t + bcol;
        int cell = c / 40, cc = c % 40;
        int m = (2 * t) / 5; if (m > 10) m = 10;
        int kg = 16 * m + k;
        int cellk = kg / 16, j = kg % 16;
        float v = (cellk == cell) ? W2[((size_t)cell * HH + j) * CC + cc] : 0.f;
        Wpack[idx] = f2b(v);
        return;
    }
    idx -= PW_W2P;
    if (idx < 192) {
        int h = idx / 48, r = (idx % 48) / 16, j = idx % 16;
        int i = (r * 4 + h) * HH + j;
        float sc = gamma[i] * rsqrtf(bn_var[i] + 1e-5f);
        shift192[idx] = (b1[i] - bn_mean[i]) * sc + beta[i];
    }
}

// ---------------- projection via MFMA with fused row L2-normalization ----------------
__global__ __launch_bounds__(256) void k_proj_mfma(const float* __restrict__ x,
                                                   const unsigned short* __restrict__ W1T,
                                                   const float* __restrict__ shift192,
                                                   unsigned short* __restrict__ Hcat,
                                                   unsigned short* __restrict__ Pg) {
    int tid = threadIdx.x;
    int wid = tid >> 6, lane = tid & 63;
    int rowbase = blockIdx.x * 64 + wid * 16;
    int arow = rowbase + (lane & 15);
    int arow_c = (arow < NN) ? arow : NN - 1;
    int kgrp = lane >> 4;
    int bcol = lane & 15;

    const float* xr = x + (size_t)arow_c * DD;
    float xreg[4][8];
    float ss = 0.f;
    #pragma unroll
    for (int kt = 0; kt < 4; kt++) {
        int k0 = kt * 32 + kgrp * 8;
        float4 va = make_float4(0.f, 0.f, 0.f, 0.f);
        float4 vb = make_float4(0.f, 0.f, 0.f, 0.f);
        if (k0 + 8 <= DD) {
            va = *(const float4*)(xr + k0);
            vb = *(const float4*)(xr + k0 + 4);
        } else if (k0 < DD) {            // k0 == 96: cols 96..99 valid
            va = *(const float4*)(xr + k0);
        }
        xreg[kt][0] = va.x; xreg[kt][1] = va.y; xreg[kt][2] = va.z; xreg[kt][3] = va.w;
        xreg[kt][4] = vb.x; xreg[kt][5] = vb.y; xreg[kt][6] = vb.z; xreg[kt][7] = vb.w;
        ss += va.x * va.x + va.y * va.y + va.z * va.z + va.w * va.w;
        ss += vb.x * vb.x + vb.y * vb.y + vb.z * vb.z + vb.w * vb.w;
    }
    ss += __shfl_xor(ss, 16);
    ss += __shfl_xor(ss, 32);
    float inv = 1.f / fmaxf(sqrtf(ss), 1e-12f);

    f32x4 acc[12];
    #pragma unroll
    for (int t = 0; t < 12; t++) acc[t] = (f32x4){0.f, 0.f, 0.f, 0.f};

    #pragma unroll
    for (int kt = 0; kt < 4; kt++) {
        int k0 = kt * 32 + kgrp * 8;
        bf16x8 afr;
        #pragma unroll
        for (int i = 0; i < 8; i++) afr[i] = (short)f2b(xreg[kt][i] * inv);
        #pragma unroll
        for (int t = 0; t < 12; t++) {
            bf16x8 bfr = *(const bf16x8*)(W1T + (size_t)(t * 16 + bcol) * 128 + k0);
            acc[t] = __builtin_amdgcn_mfma_f32_16x16x32_bf16(afr, bfr, acc[t], 0, 0, 0);
        }
    }
    int drow = rowbase + (lane >> 4) * 4;
    int lc = lane & 15;
    #pragma unroll
    for (int r = 0; r < 4; r++) {
        int grow = drow + r;
        if (grow < NN) {
            #pragma unroll
            for (int t = 0; t < 12; t++) {
                int c = t * 16 + lc;
                float v = acc[t][r];
                if (c < 48) {
                    v = fmaxf(v + shift192[c], 0.f);
                    Hcat[(size_t)grow * 192 + (c / 16) * 64 + (c % 16)] = f2b(v);
                } else {
                    Pg[(size_t)grow * 144 + (c - 48)] = f2b(v);
                }
            }
        }
    }
}

// ---------------- SpMM bf16, fused epilogue, 4-deep gather + next-batch edge prefetch ----------------
// (r13 inner loop — measured optimum; degree-sorted row permutation for wave balance)
template <int NU, int RPW, bool RELU, bool HMAP>
__global__ __launch_bounds__(256) void k_spmm(const int* __restrict__ rp, const int2* __restrict__ ecv,
                                              const float* __restrict__ dinv, const int* __restrict__ perm,
                                              const bf2* __restrict__ in, int ins,
                                              bf2* __restrict__ outA, int sA, int aoff,
                                              const float* __restrict__ shiftA,
                                              bf2* __restrict__ outB, int sB) {
    constexpr int LPR = (RPW == 1) ? 64 : 32;
    constexpr int J = (NU + LPR - 1) / LPR;
    int gw = (blockIdx.x * 256 + threadIdx.x) >> 6;
    int lane = threadIdx.x & 63;
    int sub = (RPW == 2) ? (lane >> 5) : 0;
    int su = (RPW == 2) ? (lane & 31) : lane;
    int idx = gw * RPW + sub;
    if (idx >= NN) return;
    int row = perm[idx];

    float d = dinv[row];
    float sw = d * d;
    float2 acc[J];
    {
        size_t b = (size_t)row * ins;
        #pragma unroll
        for (int j = 0; j < J; j++) {
            int u = su + LPR * j;
            if (u < NU) {
                float2 f = b2f2(in[b + u]);
                acc[j].x = sw * f.x; acc[j].y = sw * f.y;
            } else { acc[j].x = 0.f; acc[j].y = 0.f; }
        }
    }
    int s = rp[row], e = rp[row + 1];
    int p = s;
    int e4 = s + ((e - s) & ~3);
    int2 nb[4];
    if (p < e4) {
        #pragma unroll
        for (int q = 0; q < 4; q++) nb[q] = ecv[p + q];
    }
    while (p < e4) {
        int2 cb[4];
        #pragma unroll
        for (int q = 0; q < 4; q++) cb[q] = nb[q];
        int pn = p + 4;
        if (pn < e4) {                       // prefetch next batch's edges
            #pragma unroll
            for (int q = 0; q < 4; q++) nb[q] = ecv[pn + q];
        }
        bf2 rr[4][J];
        #pragma unroll
        for (int q = 0; q < 4; q++) {
            size_t b = (size_t)cb[q].x * ins;
            #pragma unroll
            for (int j = 0; j < J; j++) {
                int u = su + LPR * j;
                if (u < NU) rr[q][j] = in[b + u];
            }
        }
        #pragma unroll
        for (int q = 0; q < 4; q++) {
            float vq = __int_as_float(cb[q].y);
            #pragma unroll
            for (int j = 0; j < J; j++) {
                int u = su + LPR * j;
                if (u < NU) {
                    float2 f = b2f2(rr[q][j]);
                    acc[j].x += vq * f.x;
                    acc[j].y += vq * f.y;
                }
            }
        }
        p = pn;
    }
    while (p < e) {
        int2 ee = ecv[p];
        float v = __int_as_float(ee.y);
        size_t b = (size_t)ee.x * ins;
        #pragma unroll
        for (int j = 0; j < J; j++) {
            int u = su + LPR * j;
            if (u < NU) {
                float2 f = b2f2(in[b + u]);
                acc[j].x += v * f.x; acc[j].y += v * f.y;
            }
        }
        p++;
    }
    #pragma unroll
    for (int j = 0; j < J; j++) {
        int u = su + LPR * j;
        if (u < NU) {
            float fx = acc[j].x, fy = acc[j].y;
            if (u < 24) {
                if (RELU) {
                    fx = fmaxf(fx + shiftA[2 * u], 0.f);
                    fy = fmaxf(fy + shiftA[2 * u + 1], 0.f);
                }
                int unit = HMAP ? ((u / 8) * 32 + (u & 7) + aoff) : (u + aoff);
                outA[(size_t)row * sA + unit] = f22b2(fx, fy);
            } else {
                outB[(size_t)row * sB + (u - 24)] = f22b2(fx, fy);
            }
        }
    }
}

// ---------------- fused tail: outcell = blockdiag(Hcat@W2)+b2 ; out = relu(outcell)@Wout+bout ----------------
__global__ __launch_bounds__(256) void k_tail(const unsigned short* __restrict__ Hcat,
                                              const unsigned short* __restrict__ Wpack,
                                              const float* __restrict__ b2v,
                                              const unsigned short* __restrict__ WoutT,
                                              const float* __restrict__ bout,
                                              float* __restrict__ outcell, float* __restrict__ out) {
    __shared__ __align__(16) unsigned short hl[64][488];   // 62.4 KB; 976B row stride
    int tid = threadIdx.x;
    int wid = tid >> 6, lane = tid & 63;
    int rowbase = blockIdx.x * 64 + wid * 16;
    int arow = rowbase + (lane & 15);
    int arow_c = (arow < NN) ? arow : NN - 1;
    int kgrp = lane >> 4;
    int bcol = lane & 15;

    {
        const unsigned short* hr = Hcat + (size_t)arow_c * 192;
        bf16x8 ab[11];
        #pragma unroll
        for (int m = 0; m < 11; m++) ab[m] = *(const bf16x8*)(hr + (2 * m + kgrp) * 8);

        int drow4 = wid * 16 + (lane >> 4) * 4;
        #pragma unroll
        for (int t = 0; t < 30; t++) {
            const int m = ((2 * t) / 5 < 10) ? (2 * t) / 5 : 10;
            bf16x8 bfr = *(const bf16x8*)(Wpack + (size_t)(t * 16 + bcol) * 32 + kgrp * 8);
            f32x4 acc = {0.f, 0.f, 0.f, 0.f};
            acc = __builtin_amdgcn_mfma_f32_16x16x32_bf16(ab[m], bfr, acc, 0, 0, 0);
            int c = 16 * t + bcol;
            float bias = b2v[c];
            #pragma unroll
            for (int r = 0; r < 4; r++) {
                int grow = blockIdx.x * 64 + drow4 + r;
                float val = acc[r] + bias;
                if (grow < NN) outcell[(size_t)grow * (NCELL * CC) + c] = val;
                hl[drow4 + r][c] = f2b(fmaxf(val, 0.f));
            }
        }
    }
    __syncthreads();

    {
        f32x4 acc0 = {0.f, 0.f, 0.f, 0.f};
        f32x4 acc1 = {0.f, 0.f, 0.f, 0.f};
        f32x4 acc2 = {0.f, 0.f, 0.f, 0.f};
        const unsigned short* arl = &hl[wid * 16 + (lane & 15)][0];

        for (int kt = 0; kt < 15; kt++) {
            int k0 = kt * 32 + kgrp * 8;
            bf16x8 afr = *(const bf16x8*)(arl + k0);
            bf16x8 bf0 = *(const bf16x8*)(WoutT + (size_t)(0 * 16 + bcol) * 480 + k0);
            bf16x8 bf1 = *(const bf16x8*)(WoutT + (size_t)(1 * 16 + bcol) * 480 + k0);
            bf16x8 bf2f = *(const bf16x8*)(WoutT + (size_t)(2 * 16 + bcol) * 480 + k0);
            acc0 = __builtin_amdgcn_mfma_f32_16x16x32_bf16(afr, bf0, acc0, 0, 0, 0);
            acc1 = __builtin_amdgcn_mfma_f32_16x16x32_bf16(afr, bf1, acc1, 0, 0, 0);
            acc2 = __builtin_amdgcn_mfma_f32_16x16x32_bf16(afr, bf2f, acc2, 0, 0, 0);
        }

        int drow = rowbase + (lane >> 4) * 4;
        #pragma unroll
        for (int r = 0; r < 4; r++) {
            int grow = drow + r;
            if (grow < NN) {
                int c0 = 0 * 16 + bcol;
                int c1 = 1 * 16 + bcol;
                int c2 = 2 * 16 + bcol;
                float* o = out + (size_t)grow * CC;
                o[c0] = acc0[r] + bout[c0];
                o[c1] = acc1[r] + bout[c1];
                if (c2 < CC) o[c2] = acc2[r] + bout[c2];
            }
        }
    }
}

// ---------------- host ----------------

extern "C" void kernel_launch(void* const* d_in, const int* in_sizes, int n_in,
                              void* d_out, int out_size, void* d_ws, size_t ws_size,
                              hipStream_t stream) {
    const float* x       = (const float*)d_in[0];
    const int*   er      = (const int*)d_in[1];
    const int*   ec      = (const int*)d_in[2];
    const float* W1      = (const float*)d_in[3];
    const float* b1      = (const float*)d_in[4];
    const float* gamma   = (const float*)d_in[5];
    const float* beta    = (const float*)d_in[6];
    const float* bn_mean = (const float*)d_in[7];
    const float* bn_var  = (const float*)d_in[8];
    const float* W2      = (const float*)d_in[9];
    const float* b2v     = (const float*)d_in[10];
    const float* Wout    = (const float*)d_in[11];
    const float* bout    = (const float*)d_in[12];

    float* out     = (float*)d_out;               // [N, C] f32
    float* outcell = out + (size_t)NN * CC;       // [N, NC, C] f32

    char* w = (char*)d_ws;
    auto alloc = [&](size_t bytes) {
        void* p = (void*)w;
        w += (bytes + 255) & ~(size_t)255;
        return p;
    };
    int*   cnt    = (int*)alloc((size_t)NN * 4);
    int*   rp     = (int*)alloc((size_t)(NN + 1) * 4);
    int*   cursor = (int*)alloc((size_t)NN * 4);
    float* dinv   = (float*)alloc((size_t)NN * 4);
    int*   bsum   = (int*)alloc((size_t)(NB_SCAN + 1) * 4);
    int*   dbkt   = (int*)alloc((size_t)64 * 4);
    int*   perm   = (int*)alloc((size_t)NN * 4);
    int2*  ecv    = (int2*)alloc((size_t)EE * 8);
    bf2*   Pg     = (bf2*)alloc((size_t)NN * 72 * 4);    // proj cols 48:192
    bf2*   T      = (bf2*)alloc((size_t)NN * 72 * 4);    // relu'd inner [h1|h2|h3]
    bf2*   Rg1    = (bf2*)alloc((size_t)NN * 48 * 4);
    bf2*   Rg2    = (bf2*)alloc((size_t)NN * 24 * 4);
    bf2*   Vg1    = (bf2*)alloc((size_t)NN * 48 * 4);
    bf2*   Vg2    = (bf2*)alloc((size_t)NN * 24 * 4);
    bf2*   Hcat   = (bf2*)alloc((size_t)NN * 96 * 4);    // [N,192] cell-major
    float* shift192 = (float*)alloc((size_t)192 * 4);
    unsigned short* WoutT = (unsigned short*)alloc((size_t)48 * 480 * 2);
    unsigned short* W1T   = (unsigned short*)alloc((size_t)192 * 128 * 2);
    unsigned short* Wpack = (unsigned short*)alloc((size_t)30 * 16 * 32 * 2);

    hipMemsetAsync(cnt, 0, (size_t)NN * 4, stream);
    hipMemsetAsync(dbkt, 0, (size_t)64 * 4, stream);

    int gE = (EE + 255) / 256;
    int gN = (NN + 255) / 256;

    k_hist<<<gE, 256, 0, stream>>>(er, cnt);
    k_scan1<<<NB_SCAN, 1024, 0, stream>>>(cnt, rp, bsum);
    k_scan2<<<1, 64, 0, stream>>>(bsum);
    k_scan3<<<gN, 256, 0, stream>>>(rp, cursor, bsum, cnt, dinv, dbkt);
    k_dscan<<<1, 64, 0, stream>>>(dbkt);
    k_dfill<<<gN, 256, 0, stream>>>(cnt, dbkt, perm);
    k_fill<<<gE, 256, 0, stream>>>(er, ec, dinv, cursor, ecv);
    k_prep<<<(PW_TOTAL + 255) / 256, 256, 0, stream>>>(W1, Wout, W2, b1, gamma, beta, bn_mean, bn_var,
                                                       W1T, WoutT, Wpack, shift192);

    int g64 = (NN + 63) / 64;
    k_proj_mfma<<<g64, 256, 0, stream>>>(x, W1T, shift192, (unsigned short*)Hcat, (unsigned short*)Pg);

    int gW1 = (NN + 3) / 4;
    int gW2 = (NN + 7) / 8;
    // inner chain with fused BN-shift+relu into T
    k_spmm<72, 1, true, false><<<gW1, 256, 0, stream>>>(rp, ecv, dinv, perm, Pg, 72, T, 72, 0,  shift192 + 48,  Rg1, 48);
    k_spmm<48, 1, true, false><<<gW1, 256, 0, stream>>>(rp, ecv, dinv, perm, Rg1, 48, T, 72, 24, shift192 + 96,  Rg2, 24);
    k_spmm<24, 2, true, false><<<gW2, 256, 0, stream>>>(rp, ecv, dinv, perm, Rg2, 24, T, 72, 48, shift192 + 144, Rg1, 48);
    // outer chain writing Hcat (cell-major) directly
    k_spmm<72, 1, false, true><<<gW1, 256, 0, stream>>>(rp, ecv, dinv, perm, T, 72,   Hcat, 96, 8,  nullptr, Vg1, 48);
    k_spmm<48, 1, false, true><<<gW1, 256, 0, stream>>>(rp, ecv, dinv, perm, Vg1, 48, Hcat, 96, 16, nullptr, Vg2, 24);
    k_spmm<24, 2, false, true><<<gW2, 256, 0, stream>>>(rp, ecv, dinv, perm, Vg2, 24, Hcat, 96, 24, nullptr, Vg1, 48);

    k_tail<<<g64, 256, 0, stream>>>((const unsigned short*)Hcat, Wpack, b2v, WoutT, bout, outcell, out);
}

// Round 18
// 387.193 us; speedup vs baseline: 1.6936x; 1.6936x over previous
//
#include <hip/hip_runtime.h>
#include <hip/hip_bf16.h>

#define NN 50000
#define EE 800000
#define DD 100
#define HH 16
#define CC 40
#define NCELL 12
#define NB_SCAN 49   // ceil(50000/1024)

typedef __hip_bfloat162 bf2;
typedef short bf16x8 __attribute__((ext_vector_type(8)));
typedef float f32x4 __attribute__((ext_vector_type(4)));

__device__ __forceinline__ float2 b2f2(bf2 v) { return __bfloat1622float2(v); }
__device__ __forceinline__ bf2 f22b2(float f0, float f1) {
    float2 t; t.x = f0; t.y = f1;
    return __float22bfloat162_rn(t);
}
__device__ __forceinline__ unsigned short f2b(float f) {
    __hip_bfloat16 h = __float2bfloat16(f);
    return *reinterpret_cast<unsigned short*>(&h);
}

// ---------------- graph preprocessing ----------------

__global__ __launch_bounds__(256) void k_hist(const int* __restrict__ er, int* __restrict__ cnt) {
    int e = blockIdx.x * 256 + threadIdx.x;
    if (e < EE) atomicAdd(&cnt[er[e]], 1);
}

__global__ __launch_bounds__(1024) void k_scan1(const int* __restrict__ cnt, int* __restrict__ rp,
                                                int* __restrict__ bsum) {
    __shared__ int lds[1024];
    int t = threadIdx.x, i = blockIdx.x * 1024 + t;
    int v = (i < NN) ? cnt[i] : 0;
    lds[t] = v;
    __syncthreads();
    #pragma unroll
    for (int off = 1; off < 1024; off <<= 1) {
        int x = lds[t];
        int y = (t >= off) ? lds[t - off] : 0;
        __syncthreads();
        lds[t] = x + y;
        __syncthreads();
    }
    if (i < NN) rp[i] = lds[t] - v;
    if (t == 1023) bsum[blockIdx.x] = lds[1023];
}

__global__ __launch_bounds__(64) void k_scan2(int* __restrict__ bsum) {
    int t = threadIdx.x;
    int orig = (t < NB_SCAN) ? bsum[t] : 0;
    int v = orig;
    #pragma unroll
    for (int off = 1; off < 64; off <<= 1) {
        int y = __shfl_up(v, off);
        if (t >= off) v += y;
    }
    if (t < NB_SCAN) bsum[t] = v - orig;
    if (t == NB_SCAN - 1) bsum[NB_SCAN] = v;
}

// scan finalize + dinv (folded)
__global__ __launch_bounds__(256) void k_scan3(int* __restrict__ rp, int* __restrict__ cursor,
                                               const int* __restrict__ bsum, const int* __restrict__ cnt,
                                               float* __restrict__ dinv) {
    int i = blockIdx.x * 256 + threadIdx.x;
    if (i < NN) {
        int v = rp[i] + bsum[i >> 10];
        rp[i] = v;
        cursor[i] = v;
        dinv[i] = rsqrtf((float)(cnt[i] + 1));   // +1 self loop
    }
    if (i == 0) rp[NN] = bsum[NB_SCAN];
}

// CSR fill: single 8B scatter per edge {col, bits(val)}
__global__ __launch_bounds__(256) void k_fill(const int* __restrict__ er, const int* __restrict__ ec,
                                              const float* __restrict__ dinv, int* __restrict__ cursor,
                                              int2* __restrict__ ecv) {
    int e = blockIdx.x * 256 + threadIdx.x;
    if (e >= EE) return;
    int r = er[e], c = ec[e];
    int p = atomicAdd(&cursor[r], 1);
    float v = dinv[r] * dinv[c];
    ecv[p] = make_int2(c, __float_as_int(v));
}

// ---------------- merged weight prep: W1T | WoutT | Wpack | shift192 ----------------
#define PW_W1T   (192 * 128)
#define PW_WT    (48 * 480)
#define PW_W2P   (30 * 16 * 32)
#define PW_TOTAL (PW_W1T + PW_WT + PW_W2P + 192)
__global__ __launch_bounds__(256) void k_prep(const float* __restrict__ W1, const float* __restrict__ Wout,
                                              const float* __restrict__ W2, const float* __restrict__ b1,
                                              const float* __restrict__ gamma, const float* __restrict__ beta,
                                              const float* __restrict__ bn_mean, const float* __restrict__ bn_var,
                                              unsigned short* __restrict__ W1T, unsigned short* __restrict__ WoutT,
                                              unsigned short* __restrict__ Wpack, float* __restrict__ shift192) {
    int idx = blockIdx.x * 256 + threadIdx.x;
    if (idx < PW_W1T) {
        int c = idx / 128, k = idx % 128;
        int g = c / 48, i = c % 48;
        int cell = (i / 16) * 4 + g, j = i % 16;
        float sc = gamma[cell * HH + j] * rsqrtf(bn_var[cell * HH + j] + 1e-5f);
        float v = (k < DD) ? W1[((size_t)cell * DD + k) * HH + j] * sc : 0.f;
        W1T[idx] = f2b(v);
        return;
    }
    idx -= PW_W1T;
    if (idx < PW_WT) {
        int c = idx / 480, k = idx % 480;
        float v = (c < CC) ? Wout[(size_t)k * CC + c] : 0.f;
        WoutT[idx] = f2b(v);
        return;
    }
    idx -= PW_WT;
    if (idx < PW_W2P) {
        int t = idx / 512, bcol = (idx / 32) % 16, k = idx % 32;
        int c = 16 * t + bcol;
        int cell = c / 40, cc = c % 40;
        int m = (2 * t) / 5; if (m > 10) m = 10;
        int kg = 16 * m + k;
        int cellk = kg / 16, j = kg % 16;
        float v = (cellk == cell) ? W2[((size_t)cell * HH + j) * CC + cc] : 0.f;
        Wpack[idx] = f2b(v);
        return;
    }
    idx -= PW_W2P;
    if (idx < 192) {
        int h = idx / 48, r = (idx % 48) / 16, j = idx % 16;
        int i = (r * 4 + h) * HH + j;
        float sc = gamma[i] * rsqrtf(bn_var[i] + 1e-5f);
        shift192[idx] = (b1[i] - bn_mean[i]) * sc + beta[i];
    }
}

// ---------------- projection via MFMA with fused row L2-normalization ----------------
__global__ __launch_bounds__(256) void k_proj_mfma(const float* __restrict__ x,
                                                   const unsigned short* __restrict__ W1T,
                                                   const float* __restrict__ shift192,
                                                   unsigned short* __restrict__ Hcat,
                                                   unsigned short* __restrict__ Pg) {
    int tid = threadIdx.x;
    int wid = tid >> 6, lane = tid & 63;
    int rowbase = blockIdx.x * 64 + wid * 16;
    int arow = rowbase + (lane & 15);
    int arow_c = (arow < NN) ? arow : NN - 1;
    int kgrp = lane >> 4;
    int bcol = lane & 15;

    const float* xr = x + (size_t)arow_c * DD;
    float xreg[4][8];
    float ss = 0.f;
    #pragma unroll
    for (int kt = 0; kt < 4; kt++) {
        int k0 = kt * 32 + kgrp * 8;
        float4 va = make_float4(0.f, 0.f, 0.f, 0.f);
        float4 vb = make_float4(0.f, 0.f, 0.f, 0.f);
        if (k0 + 8 <= DD) {
            va = *(const float4*)(xr + k0);
            vb = *(const float4*)(xr + k0 + 4);
        } else if (k0 < DD) {            // k0 == 96: cols 96..99 valid
            va = *(const float4*)(xr + k0);
        }
        xreg[kt][0] = va.x; xreg[kt][1] = va.y; xreg[kt][2] = va.z; xreg[kt][3] = va.w;
        xreg[kt][4] = vb.x; xreg[kt][5] = vb.y; xreg[kt][6] = vb.z; xreg[kt][7] = vb.w;
        ss += va.x * va.x + va.y * va.y + va.z * va.z + va.w * va.w;
        ss += vb.x * vb.x + vb.y * vb.y + vb.z * vb.z + vb.w * vb.w;
    }
    ss += __shfl_xor(ss, 16);
    ss += __shfl_xor(ss, 32);
    float inv = 1.f / fmaxf(sqrtf(ss), 1e-12f);

    f32x4 acc[12];
    #pragma unroll
    for (int t = 0; t < 12; t++) acc[t] = (f32x4){0.f, 0.f, 0.f, 0.f};

    #pragma unroll
    for (int kt = 0; kt < 4; kt++) {
        int k0 = kt * 32 + kgrp * 8;
        bf16x8 afr;
        #pragma unroll
        for (int i = 0; i < 8; i++) afr[i] = (short)f2b(xreg[kt][i] * inv);
        #pragma unroll
        for (int t = 0; t < 12; t++) {
            bf16x8 bfr = *(const bf16x8*)(W1T + (size_t)(t * 16 + bcol) * 128 + k0);
            acc[t] = __builtin_amdgcn_mfma_f32_16x16x32_bf16(afr, bfr, acc[t], 0, 0, 0);
        }
    }
    int drow = rowbase + (lane >> 4) * 4;
    int lc = lane & 15;
    #pragma unroll
    for (int r = 0; r < 4; r++) {
        int grow = drow + r;
        if (grow < NN) {
            #pragma unroll
            for (int t = 0; t < 12; t++) {
                int c = t * 16 + lc;
                float v = acc[t][r];
                if (c < 48) {
                    v = fmaxf(v + shift192[c], 0.f);
                    Hcat[(size_t)grow * 192 + (c / 16) * 64 + (c % 16)] = f2b(v);
                } else {
                    Pg[(size_t)grow * 144 + (c - 48)] = f2b(v);
                }
            }
        }
    }
}

// ---------------- SpMM bf16, fused epilogue, 4-deep gather + next-batch edge prefetch ----------------
// (r13 inner loop — measured optimum across r14/r16/r17 variants)
template <int NU, int RPW, bool RELU, bool HMAP>
__global__ __launch_bounds__(256) void k_spmm(const int* __restrict__ rp, const int2* __restrict__ ecv,
                                              const float* __restrict__ dinv,
                                              const bf2* __restrict__ in, int ins,
                                              bf2* __restrict__ outA, int sA, int aoff,
                                              const float* __restrict__ shiftA,
                                              bf2* __restrict__ outB, int sB) {
    constexpr int LPR = (RPW == 1) ? 64 : 32;
    constexpr int J = (NU + LPR - 1) / LPR;
    int gw = (blockIdx.x * 256 + threadIdx.x) >> 6;
    int lane = threadIdx.x & 63;
    int sub = (RPW == 2) ? (lane >> 5) : 0;
    int su = (RPW == 2) ? (lane & 31) : lane;
    int row = gw * RPW + sub;
    if (row >= NN) return;

    float d = dinv[row];
    float sw = d * d;
    float2 acc[J];
    {
        size_t b = (size_t)row * ins;
        #pragma unroll
        for (int j = 0; j < J; j++) {
            int u = su + LPR * j;
            if (u < NU) {
                float2 f = b2f2(in[b + u]);
                acc[j].x = sw * f.x; acc[j].y = sw * f.y;
            } else { acc[j].x = 0.f; acc[j].y = 0.f; }
        }
    }
    int s = rp[row], e = rp[row + 1];
    int p = s;
    int e4 = s + ((e - s) & ~3);
    int2 nb[4];
    if (p < e4) {
        #pragma unroll
        for (int q = 0; q < 4; q++) nb[q] = ecv[p + q];
    }
    while (p < e4) {
        int2 cb[4];
        #pragma unroll
        for (int q = 0; q < 4; q++) cb[q] = nb[q];
        int pn = p + 4;
        if (pn < e4) {                       // prefetch next batch's edges
            #pragma unroll
            for (int q = 0; q < 4; q++) nb[q] = ecv[pn + q];
        }
        bf2 rr[4][J];
        #pragma unroll
        for (int q = 0; q < 4; q++) {
            size_t b = (size_t)cb[q].x * ins;
            #pragma unroll
            for (int j = 0; j < J; j++) {
                int u = su + LPR * j;
                if (u < NU) rr[q][j] = in[b + u];
            }
        }
        #pragma unroll
        for (int q = 0; q < 4; q++) {
            float vq = __int_as_float(cb[q].y);
            #pragma unroll
            for (int j = 0; j < J; j++) {
                int u = su + LPR * j;
                if (u < NU) {
                    float2 f = b2f2(rr[q][j]);
                    acc[j].x += vq * f.x;
                    acc[j].y += vq * f.y;
                }
            }
        }
        p = pn;
    }
    while (p < e) {
        int2 ee = ecv[p];
        float v = __int_as_float(ee.y);
        size_t b = (size_t)ee.x * ins;
        #pragma unroll
        for (int j = 0; j < J; j++) {
            int u = su + LPR * j;
            if (u < NU) {
                float2 f = b2f2(in[b + u]);
                acc[j].x += v * f.x; acc[j].y += v * f.y;
            }
        }
        p++;
    }
    #pragma unroll
    for (int j = 0; j < J; j++) {
        int u = su + LPR * j;
        if (u < NU) {
            float fx = acc[j].x, fy = acc[j].y;
            if (u < 24) {
                if (RELU) {
                    fx = fmaxf(fx + shiftA[2 * u], 0.f);
                    fy = fmaxf(fy + shiftA[2 * u + 1], 0.f);
                }
                int unit = HMAP ? ((u / 8) * 32 + (u & 7) + aoff) : (u + aoff);
                outA[(size_t)row * sA + unit] = f22b2(fx, fy);
            } else {
                outB[(size_t)row * sB + (u - 24)] = f22b2(fx, fy);
            }
        }
    }
}

// ---------------- fused tail: outcell = blockdiag(Hcat@W2)+b2 ; out = relu(outcell)@Wout+bout ----------------
__global__ __launch_bounds__(256) void k_tail(const unsigned short* __restrict__ Hcat,
                                              const unsigned short* __restrict__ Wpack,
                                              const float* __restrict__ b2v,
                                              const unsigned short* __restrict__ WoutT,
                                              const float* __restrict__ bout,
                                              float* __restrict__ outcell, float* __restrict__ out) {
    __shared__ __align__(16) unsigned short hl[64][488];   // 62.4 KB; 976B row stride
    int tid = threadIdx.x;
    int wid = tid >> 6, lane = tid & 63;
    int rowbase = blockIdx.x * 64 + wid * 16;
    int arow = rowbase + (lane & 15);
    int arow_c = (arow < NN) ? arow : NN - 1;
    int kgrp = lane >> 4;
    int bcol = lane & 15;

    {
        const unsigned short* hr = Hcat + (size_t)arow_c * 192;
        bf16x8 ab[11];
        #pragma unroll
        for (int m = 0; m < 11; m++) ab[m] = *(const bf16x8*)(hr + (2 * m + kgrp) * 8);

        int drow4 = wid * 16 + (lane >> 4) * 4;
        #pragma unroll
        for (int t = 0; t < 30; t++) {
            const int m = ((2 * t) / 5 < 10) ? (2 * t) / 5 : 10;
            bf16x8 bfr = *(const bf16x8*)(Wpack + (size_t)(t * 16 + bcol) * 32 + kgrp * 8);
            f32x4 acc = {0.f, 0.f, 0.f, 0.f};
            acc = __builtin_amdgcn_mfma_f32_16x16x32_bf16(ab[m], bfr, acc, 0, 0, 0);
            int c = 16 * t + bcol;
            float bias = b2v[c];
            #pragma unroll
            for (int r = 0; r < 4; r++) {
                int grow = blockIdx.x * 64 + drow4 + r;
                float val = acc[r] + bias;
                if (grow < NN) outcell[(size_t)grow * (NCELL * CC) + c] = val;
                hl[drow4 + r][c] = f2b(fmaxf(val, 0.f));
            }
        }
    }
    __syncthreads();

    {
        f32x4 acc0 = {0.f, 0.f, 0.f, 0.f};
        f32x4 acc1 = {0.f, 0.f, 0.f, 0.f};
        f32x4 acc2 = {0.f, 0.f, 0.f, 0.f};
        const unsigned short* arl = &hl[wid * 16 + (lane & 15)][0];

        for (int kt = 0; kt < 15; kt++) {
            int k0 = kt * 32 + kgrp * 8;
            bf16x8 afr = *(const bf16x8*)(arl + k0);
            bf16x8 bf0 = *(const bf16x8*)(WoutT + (size_t)(0 * 16 + bcol) * 480 + k0);
            bf16x8 bf1 = *(const bf16x8*)(WoutT + (size_t)(1 * 16 + bcol) * 480 + k0);
            bf16x8 bf2f = *(const bf16x8*)(WoutT + (size_t)(2 * 16 + bcol) * 480 + k0);
            acc0 = __builtin_amdgcn_mfma_f32_16x16x32_bf16(afr, bf0, acc0, 0, 0, 0);
            acc1 = __builtin_amdgcn_mfma_f32_16x16x32_bf16(afr, bf1, acc1, 0, 0, 0);
            acc2 = __builtin_amdgcn_mfma_f32_16x16x32_bf16(afr, bf2f, acc2, 0, 0, 0);
        }

        int drow = rowbase + (lane >> 4) * 4;
        #pragma unroll
        for (int r = 0; r < 4; r++) {
            int grow = drow + r;
            if (grow < NN) {
                int c0 = 0 * 16 + bcol;
                int c1 = 1 * 16 + bcol;
                int c2 = 2 * 16 + bcol;
                float* o = out + (size_t)grow * CC;
                o[c0] = acc0[r] + bout[c0];
                o[c1] = acc1[r] + bout[c1];
                if (c2 < CC) o[c2] = acc2[r] + bout[c2];
            }
        }
    }
}

// ---------------- host ----------------

extern "C" void kernel_launch(void* const* d_in, const int* in_sizes, int n_in,
                              void* d_out, int out_size, void* d_ws, size_t ws_size,
                              hipStream_t stream) {
    const float* x       = (const float*)d_in[0];
    const int*   er      = (const int*)d_in[1];
    const int*   ec      = (const int*)d_in[2];
    const float* W1      = (const float*)d_in[3];
    const float* b1      = (const float*)d_in[4];
    const float* gamma   = (const float*)d_in[5];
    const float* beta    = (const float*)d_in[6];
    const float* bn_mean = (const float*)d_in[7];
    const float* bn_var  = (const float*)d_in[8];
    const float* W2      = (const float*)d_in[9];
    const float* b2v     = (const float*)d_in[10];
    const float* Wout    = (const float*)d_in[11];
    const float* bout    = (const float*)d_in[12];

    float* out     = (float*)d_out;               // [N, C] f32
    float* outcell = out + (size_t)NN * CC;       // [N, NC, C] f32

    char* w = (char*)d_ws;
    auto alloc = [&](size_t bytes) {
        void* p = (void*)w;
        w += (bytes + 255) & ~(size_t)255;
        return p;
    };
    int*   cnt    = (int*)alloc((size_t)NN * 4);
    int*   rp     = (int*)alloc((size_t)(NN + 1) * 4);
    int*   cursor = (int*)alloc((size_t)NN * 4);
    float* dinv   = (float*)alloc((size_t)NN * 4);
    int*   bsum   = (int*)alloc((size_t)(NB_SCAN + 1) * 4);
    int2*  ecv    = (int2*)alloc((size_t)EE * 8);
    bf2*   Pg     = (bf2*)alloc((size_t)NN * 72 * 4);    // proj cols 48:192
    bf2*   T      = (bf2*)alloc((size_t)NN * 72 * 4);    // relu'd inner [h1|h2|h3]
    bf2*   Rg1    = (bf2*)alloc((size_t)NN * 48 * 4);
    bf2*   Rg2    = (bf2*)alloc((size_t)NN * 24 * 4);
    bf2*   Vg1    = (bf2*)alloc((size_t)NN * 48 * 4);
    bf2*   Vg2    = (bf2*)alloc((size_t)NN * 24 * 4);
    bf2*   Hcat   = (bf2*)alloc((size_t)NN * 96 * 4);    // [N,192] cell-major
    float* shift192 = (float*)alloc((size_t)192 * 4);
    unsigned short* WoutT = (unsigned short*)alloc((size_t)48 * 480 * 2);
    unsigned short* W1T   = (unsigned short*)alloc((size_t)192 * 128 * 2);
    unsigned short* Wpack = (unsigned short*)alloc((size_t)30 * 16 * 32 * 2);

    hipMemsetAsync(cnt, 0, (size_t)NN * 4, stream);

    int gE = (EE + 255) / 256;
    int gN = (NN + 255) / 256;

    k_hist<<<gE, 256, 0, stream>>>(er, cnt);
    k_scan1<<<NB_SCAN, 1024, 0, stream>>>(cnt, rp, bsum);
    k_scan2<<<1, 64, 0, stream>>>(bsum);
    k_scan3<<<gN, 256, 0, stream>>>(rp, cursor, bsum, cnt, dinv);
    k_fill<<<gE, 256, 0, stream>>>(er, ec, dinv, cursor, ecv);
    k_prep<<<(PW_TOTAL + 255) / 256, 256, 0, stream>>>(W1, Wout, W2, b1, gamma, beta, bn_mean, bn_var,
                                                       W1T, WoutT, Wpack, shift192);

    int g64 = (NN + 63) / 64;
    k_proj_mfma<<<g64, 256, 0, stream>>>(x, W1T, shift192, (unsigned short*)Hcat, (unsigned short*)Pg);

    int gW1 = (NN + 3) / 4;
    int gW2 = (NN + 7) / 8;
    // inner chain with fused BN-shift+relu into T
    k_spmm<72, 1, true, false><<<gW1, 256, 0, stream>>>(rp, ecv, dinv, Pg, 72, T, 72, 0,  shift192 + 48,  Rg1, 48);
    k_spmm<48, 1, true, false><<<gW1, 256, 0, stream>>>(rp, ecv, dinv, Rg1, 48, T, 72, 24, shift192 + 96,  Rg2, 24);
    k_spmm<24, 2, true, false><<<gW2, 256, 0, stream>>>(rp, ecv, dinv, Rg2, 24, T, 72, 48, shift192 + 144, Rg1, 48);
    // outer chain writing Hcat (cell-major) directly
    k_spmm<72, 1, false, true><<<gW1, 256, 0, stream>>>(rp, ecv, dinv, T, 72,   Hcat, 96, 8,  nullptr, Vg1, 48);
    k_spmm<48, 1, false, true><<<gW1, 256, 0, stream>>>(rp, ecv, dinv, Vg1, 48, Hcat, 96, 16, nullptr, Vg2, 24);
    k_spmm<24, 2, false, true><<<gW2, 256, 0, stream>>>(rp, ecv, dinv, Vg2, 24, Hcat, 96, 24, nullptr, Vg1, 48);

    k_tail<<<g64, 256, 0, stream>>>((const unsigned short*)Hcat, Wpack, b2v, WoutT, bout, outcell, out);
}